// Round 15
// baseline (170.078 us; speedup 1.0000x reference)
//
#include <hip/hip_runtime.h>

// out = segment_sum( coef(e_feat) * (emb[src] ⊙ weight), dst, N )
// coef(v) = sw[0] + (v==0)*sw[1] + (v==2)*sw[2] + (v==4)*sw[3] + (v==6)*sw[4]
//
// R15 = R12 split structure (measured best: 158us, gather 57us) with k_bin
// rebuilt for occupancy:
//   k_bin:     CHUNK=2048, 256thr, grid=489 (~2 blk/CU vs R12's 1), coarse
//              buckets of 512 nodes (nbukc=196) -> 256-entry scan, 13KB LDS,
//              runs ~10 recs (coalesced), line-padded cursors.
//   k_regroup: 4 blocks per coarse bucket (grid 784); each filters its
//              128-node sub-range (2 L2-hot passes), LDS-sorts by node,
//              writes recs2 + meta (as R12).
//   k_gather:  byte-identical to R12 (57us measured).
// Record (u32): src(17) | dst&511 (9)<<17 | ef(3)<<26.

#define DIM 64
#define LOGC 9
#define NPC 512                 // nodes per coarse bucket
#define NBC_MAX 256
#define CAPC 6144               // records per coarse bucket (mean ~5120... actually mean 2048*... mean E/nbukc ~5102)
#define CHUNK 2048              // edges per bin block
#define NPB2 128                // nodes per regroup sub-block
#define CAP2 2048               // recs2 slots per sub-block (mean ~1280)
#define OVF_CAP 8192
#define CURSOR_STRIDE 16        // 1 cursor per 64B line

// ---------------- pass A: coarse binning, occupancy-tuned ----------------
__global__ __launch_bounds__(256) void k_bin(
    const int* __restrict__ e_feat, const int* __restrict__ src_idx,
    const int* __restrict__ dst_idx,
    int* __restrict__ cursor, int* __restrict__ ovf_cnt, int4* __restrict__ ovf,
    unsigned int* __restrict__ recs, int E, int nbukc)
{
    __shared__ int hist[NBC_MAX];
    __shared__ int ss[NBC_MAX];
    __shared__ int adjs[NBC_MAX];
    __shared__ unsigned int stage_rec[CHUNK];
    __shared__ unsigned char stage_b[CHUNK];

    const int t = threadIdx.x;
    const int base = blockIdx.x * CHUNK;
    int n = E - base; if (n > CHUNK) n = CHUNK;

    hist[t] = 0;
    __syncthreads();

    unsigned int rec[8]; int bk[8]; int lr[8];
    #pragma unroll
    for (int k = 0; k < 8; ++k) {
        int i = t + k * 256;
        if (i < n) {
            int j = base + i;
            int d = dst_idx[j];
            int s = src_idx[j];
            int f = e_feat[j];
            bk[k]  = d >> LOGC;
            rec[k] = (unsigned)s | ((unsigned)(d & (NPC - 1)) << 17)
                                 | ((unsigned)f << 26);
            lr[k]  = atomicAdd(&hist[bk[k]], 1);
        } else bk[k] = -1;
    }
    __syncthreads();

    // inclusive scan of hist[0..256) (one entry per thread, 8 iters)
    ss[t] = hist[t];
    __syncthreads();
    for (int off = 1; off < NBC_MAX; off <<= 1) {
        int v = (t >= off) ? ss[t - off] : 0;
        __syncthreads();
        ss[t] += v;
        __syncthreads();
    }
    // exclusive start of bucket b = ss[b] - hist[b]

    #pragma unroll
    for (int k = 0; k < 8; ++k) {
        if (bk[k] >= 0) {
            int pos = ss[bk[k]] - hist[bk[k]] + lr[k];
            stage_rec[pos] = rec[k];
            stage_b[pos]   = (unsigned char)bk[k];
        }
    }
    // one padded-cursor bump per (block,bucket)
    if (t < nbukc) {
        int c = hist[t];
        if (c > 0) {
            int g0 = atomicAdd(&cursor[t * CURSOR_STRIDE], c);
            adjs[t] = g0 - (ss[t] - c);
        }
    }
    __syncthreads();

    // coalesced copy: consecutive i -> consecutive positions within runs
    for (int i = t; i < n; i += 256) {
        int b  = stage_b[i];
        int dp = adjs[b] + i;
        unsigned int r = stage_rec[i];
        if (dp < CAPC) {
            recs[(size_t)b * CAPC + dp] = r;
        } else {
            int oi = atomicAdd(ovf_cnt, 1);
            if (oi < OVF_CAP) {
                int s  = r & 0x1FFFF;
                int dl = (r >> 17) & (NPC - 1);
                int f  = (r >> 26) & 7;
                ovf[oi] = make_int4((b << LOGC) | dl, s, f, 0);
            }
        }
    }
}

// ---------------- pass B: sub-range filter + node-sort + meta ----------------
__global__ __launch_bounds__(256) void k_regroup(
    const int* __restrict__ cursor, const unsigned int* __restrict__ recs,
    const float* __restrict__ sw,
    int2* __restrict__ recs2, int2* __restrict__ meta, int N)
{
    __shared__ int hist2[NPB2];
    __shared__ int cur[NPB2];
    __shared__ int nstart[NPB2];
    __shared__ int2 rbuf[CAP2];              // 16 KB

    const int t   = threadIdx.x;
    const int bid = blockIdx.x;
    const int cb  = bid >> 2;                // coarse bucket
    const int sub = bid & 3;                 // 128-node sub-range

    int cnt = cursor[cb * CURSOR_STRIDE]; if (cnt > CAPC) cnt = CAPC;
    const unsigned int* rp = recs + (size_t)cb * CAPC;

    if (t < NPB2) hist2[t] = 0;
    __syncthreads();

    // pass 1: count sub-range records per node
    for (int i = t; i < cnt; i += 256) {
        unsigned int r = rp[i];
        int dl = (r >> 17) & (NPC - 1);
        if ((dl >> 7) == sub) atomicAdd(&hist2[dl & (NPB2 - 1)], 1);
    }
    __syncthreads();

    // exclusive scan of hist2[0..128)
    if (t < NPB2) cur[t] = hist2[t];
    __syncthreads();
    for (int off = 1; off < NPB2; off <<= 1) {
        int v = (t < NPB2 && t >= off) ? cur[t - off] : 0;
        __syncthreads();
        if (t < NPB2) cur[t] += v;
        __syncthreads();
    }
    if (t < NPB2) { nstart[t] = cur[t] - hist2[t]; cur[t] = nstart[t]; }
    __syncthreads();

    float s0 = sw[0], s1 = sw[1], s2 = sw[2], s3 = sw[3], s4 = sw[4];

    // pass 2: place records into rbuf grouped by node
    for (int i = t; i < cnt; i += 256) {
        unsigned int r = rp[i];
        int dl = (r >> 17) & (NPC - 1);
        if ((dl >> 7) == sub) {
            int f = (r >> 26) & 7;
            float c = s0;
            c += (f == 0) ? s1 : 0.0f;
            c += (f == 2) ? s2 : 0.0f;
            c += (f == 4) ? s3 : 0.0f;
            c += (f == 6) ? s4 : 0.0f;
            int pos = atomicAdd(&cur[dl & (NPB2 - 1)], 1);
            if (pos < CAP2)
                rbuf[pos] = make_int2((int)(r & 0x1FFFF), __float_as_int(c));
        }
    }
    __syncthreads();

    int tot = nstart[NPB2 - 1] + hist2[NPB2 - 1]; if (tot > CAP2) tot = CAP2;
    for (int i = t; i < tot; i += 256)
        recs2[(size_t)bid * CAP2 + i] = rbuf[i];

    const int node0 = (cb << LOGC) + sub * NPB2;
    if (t < NPB2) {
        int node = node0 + t;
        if (node < N) {
            int st = nstart[t]; if (st > CAP2) st = CAP2;
            int nc = hist2[t];  if (st + nc > CAP2) nc = CAP2 - st;
            meta[node] = make_int2(bid * CAP2 + st, nc);
        }
    }
}

// ---------------- pass C: wave-per-node gather (byte-identical to R12) ----------------
__global__ __launch_bounds__(256) void k_gather(
    const float* __restrict__ emb, const float* __restrict__ weight,
    const int2* __restrict__ meta, const int2* __restrict__ recs2,
    float* __restrict__ out, int N)
{
    int wave = threadIdx.x >> 6;
    int lane = threadIdx.x & 63;
    int node = blockIdx.x * 4 + wave;
    if (node >= N) return;

    int2 m = meta[node];
    int s = m.x, cnt = m.y;

    float a0=0.f,a1=0.f,a2=0.f,a3=0.f,a4=0.f,a5=0.f,a6=0.f,a7=0.f;

    for (int base = 0; base < cnt; base += 64) {
        int nch = cnt - base; if (nch > 64) nch = 64;
        int2 r = make_int2(0, 0);
        if (lane < nch) r = recs2[s + base + lane];
        int j = 0;
        for (; j + 7 < nch; j += 8) {
            int   s0 = __shfl(r.x, j    ), s1 = __shfl(r.x, j + 1);
            int   s2 = __shfl(r.x, j + 2), s3 = __shfl(r.x, j + 3);
            int   s4 = __shfl(r.x, j + 4), s5 = __shfl(r.x, j + 5);
            int   s6 = __shfl(r.x, j + 6), s7 = __shfl(r.x, j + 7);
            float c0 = __int_as_float(__shfl(r.y, j    ));
            float c1 = __int_as_float(__shfl(r.y, j + 1));
            float c2 = __int_as_float(__shfl(r.y, j + 2));
            float c3 = __int_as_float(__shfl(r.y, j + 3));
            float c4 = __int_as_float(__shfl(r.y, j + 4));
            float c5 = __int_as_float(__shfl(r.y, j + 5));
            float c6 = __int_as_float(__shfl(r.y, j + 6));
            float c7 = __int_as_float(__shfl(r.y, j + 7));
            a0 = fmaf(c0, emb[(size_t)s0 * DIM + lane], a0);
            a1 = fmaf(c1, emb[(size_t)s1 * DIM + lane], a1);
            a2 = fmaf(c2, emb[(size_t)s2 * DIM + lane], a2);
            a3 = fmaf(c3, emb[(size_t)s3 * DIM + lane], a3);
            a4 = fmaf(c4, emb[(size_t)s4 * DIM + lane], a4);
            a5 = fmaf(c5, emb[(size_t)s5 * DIM + lane], a5);
            a6 = fmaf(c6, emb[(size_t)s6 * DIM + lane], a6);
            a7 = fmaf(c7, emb[(size_t)s7 * DIM + lane], a7);
        }
        for (; j < nch; ++j) {
            int   sj = __shfl(r.x, j);
            float cj = __int_as_float(__shfl(r.y, j));
            a0 = fmaf(cj, emb[(size_t)sj * DIM + lane], a0);
        }
    }
    float acc = ((a0 + a1) + (a2 + a3)) + ((a4 + a5) + (a6 + a7));
    out[(size_t)node * DIM + lane] = acc * weight[lane];
}

// ---------------- pass D: overflow fixup (normally zero work) ----------------
__global__ __launch_bounds__(64) void k_overflow(
    const int* __restrict__ ovf_cnt, const int4* __restrict__ ovf,
    const float* __restrict__ emb, const float* __restrict__ weight,
    const float* __restrict__ sw, float* __restrict__ out)
{
    int m = *ovf_cnt; if (m > OVF_CAP) m = OVF_CAP;
    int lane = threadIdx.x;
    float s0 = sw[0], s1 = sw[1], s2 = sw[2], s3 = sw[3], s4 = sw[4];
    for (int i = blockIdx.x; i < m; i += gridDim.x) {
        int4 rec = ovf[i];
        int f = rec.z;
        float c = s0;
        c += (f == 0) ? s1 : 0.0f;
        c += (f == 2) ? s2 : 0.0f;
        c += (f == 4) ? s3 : 0.0f;
        c += (f == 6) ? s4 : 0.0f;
        float v = emb[(size_t)rec.y * DIM + lane] * weight[lane] * c;
        atomicAdd(&out[(size_t)rec.x * DIM + lane], v);
    }
}

// ---------------- fallback (tiny ws): round-1 atomic kernel ----------------
__global__ __launch_bounds__(256) void edge_scatter_kernel(
    const float* __restrict__ emb, const int* __restrict__ e_feat,
    const int* __restrict__ src_idx, const int* __restrict__ dst_idx,
    const float* __restrict__ weight, const float* __restrict__ sw,
    float* __restrict__ out, int n_edges) {
    int tid = blockIdx.x * blockDim.x + threadIdx.x;
    int edge = tid >> 4;
    int quad = tid & 15;
    if (edge >= n_edges) return;
    int ef = e_feat[edge];
    float coef = sw[0];
    coef += (ef == 0) ? sw[1] : 0.0f;
    coef += (ef == 2) ? sw[2] : 0.0f;
    coef += (ef == 4) ? sw[3] : 0.0f;
    coef += (ef == 6) ? sw[4] : 0.0f;
    int src = src_idx[edge], dst = dst_idx[edge];
    const float4 ev = *reinterpret_cast<const float4*>(emb + (size_t)src * DIM + quad * 4);
    const float4 wv = *reinterpret_cast<const float4*>(weight + quad * 4);
    float* op = out + (size_t)dst * DIM + quad * 4;
    atomicAdd(op + 0, ev.x * wv.x * coef);
    atomicAdd(op + 1, ev.y * wv.y * coef);
    atomicAdd(op + 2, ev.z * wv.z * coef);
    atomicAdd(op + 3, ev.w * wv.w * coef);
}

extern "C" void kernel_launch(void* const* d_in, const int* in_sizes, int n_in,
                              void* d_out, int out_size, void* d_ws, size_t ws_size,
                              hipStream_t stream) {
    const float* emb     = (const float*)d_in[0];
    const int*   e_feat  = (const int*)d_in[1];
    const int*   src_idx = (const int*)d_in[2];
    const int*   dst_idx = (const int*)d_in[3];
    const float* weight  = (const float*)d_in[4];
    const float* sw      = (const float*)d_in[5];
    float* out = (float*)d_out;

    const int E = in_sizes[1];
    const int N = in_sizes[0] / DIM;
    const int nbukc = (N + NPC - 1) / NPC;   // 196 for N=100000

    // ws: cursor[nbukc*16] | ovf_cnt | ovf[OVF_CAP] | recs[nbukc*CAPC] u32
    //     | recs2[nbukc*4*CAP2] int2 | meta[N] int2
    size_t off_cursor = 0;
    size_t off_ovfcnt = off_cursor + (size_t)nbukc * CURSOR_STRIDE * 4;
    size_t off_ovf    = (off_ovfcnt + 4 + 15) & ~(size_t)15;
    size_t off_recs   = (off_ovf + (size_t)OVF_CAP * 16 + 15) & ~(size_t)15;
    size_t off_recs2  = (off_recs + (size_t)nbukc * CAPC * 4 + 15) & ~(size_t)15;
    size_t off_meta   = (off_recs2 + (size_t)nbukc * 4 * CAP2 * 8 + 15) & ~(size_t)15;
    size_t needed     = off_meta + (size_t)N * 8;

    if (nbukc > NBC_MAX || ws_size < needed) {
        hipMemsetAsync(d_out, 0, (size_t)out_size * sizeof(float), stream);
        int total = E * 16, block = 256;
        edge_scatter_kernel<<<(total + block - 1) / block, block, 0, stream>>>(
            emb, e_feat, src_idx, dst_idx, weight, sw, out, E);
        return;
    }

    char* ws = (char*)d_ws;
    int*          cursor  = (int*)(ws + off_cursor);
    int*          ovf_cnt = (int*)(ws + off_ovfcnt);
    int4*         ovf     = (int4*)(ws + off_ovf);
    unsigned int* recs    = (unsigned int*)(ws + off_recs);
    int2*         recs2   = (int2*)(ws + off_recs2);
    int2*         meta    = (int2*)(ws + off_meta);

    // zero padded cursors + overflow counter (contiguous region)
    hipMemsetAsync(cursor, 0, off_ovfcnt + 16 - off_cursor, stream);

    k_bin<<<(E + CHUNK - 1) / CHUNK, 256, 0, stream>>>(
        e_feat, src_idx, dst_idx, cursor, ovf_cnt, ovf, recs, E, nbukc);

    k_regroup<<<nbukc * 4, 256, 0, stream>>>(cursor, recs, sw, recs2, meta, N);

    k_gather<<<(N + 3) / 4, 256, 0, stream>>>(emb, weight, meta, recs2, out, N);

    k_overflow<<<64, 64, 0, stream>>>(ovf_cnt, ovf, emb, weight, sw, out);
}

// Round 16
// 166.125 us; speedup vs baseline: 1.0238x; 1.0238x over previous
//
#include <hip/hip_runtime.h>

// out = segment_sum( coef(e_feat) * (emb[src] ⊙ weight), dst, N )
// coef(v) = sw[0] + (v==0)*sw[1] + (v==2)*sw[2] + (v==4)*sw[3] + (v==6)*sw[4]
//
// R16 = R12 pipeline (measured best 158us; bin+regroup byte-equivalent) with
// the gather's traffic compressed:
//   - k_convert: emb fp32 -> bf16 table in ws (25.6->12.8MB, ~8us stream).
//   - records: 4B u32 = src(17) | ef(3)<<17 (coef has 5 values -> LUT in LDS).
//   - k_gather_bf16: 128B rows + 4B recs; fp32 accumulate; out = acc*w.
//   - runtime fallback to fp32 gather if ws can't hold emb16.

#define DIM 64
#define LOGB 7
#define NPB 128
#define NBUK_MAX 1024
#define CAP 2048
#define CHUNK 4096
#define OVF_CAP 8192

// ---------------- pass 0: emb fp32 -> bf16 (RNE) ----------------
__global__ __launch_bounds__(256) void k_convert(
    const float* __restrict__ emb, unsigned short* __restrict__ emb16, int total4)
{
    int i = blockIdx.x * blockDim.x + threadIdx.x;
    if (i >= total4) return;
    float4 v = reinterpret_cast<const float4*>(emb)[i];
    ushort4 o;
    unsigned int x;
    x = __float_as_uint(v.x); o.x = (unsigned short)((x + 0x7FFF + ((x >> 16) & 1)) >> 16);
    x = __float_as_uint(v.y); o.y = (unsigned short)((x + 0x7FFF + ((x >> 16) & 1)) >> 16);
    x = __float_as_uint(v.z); o.z = (unsigned short)((x + 0x7FFF + ((x >> 16) & 1)) >> 16);
    x = __float_as_uint(v.w); o.w = (unsigned short)((x + 0x7FFF + ((x >> 16) & 1)) >> 16);
    reinterpret_cast<ushort4*>(emb16)[i] = o;
}

// ---------------- pass A: LDS-staged binning (byte-identical to R12) ----------------
__global__ __launch_bounds__(512) void k_bin(
    const int* __restrict__ e_feat, const int* __restrict__ src_idx,
    const int* __restrict__ dst_idx,
    int* __restrict__ cursor, int* __restrict__ ovf_cnt, int4* __restrict__ ovf,
    unsigned int* __restrict__ recs, int E, int nbuk)
{
    __shared__ int hist[NBUK_MAX];
    __shared__ int start[NBUK_MAX];
    __shared__ int adjs[NBUK_MAX];
    __shared__ int partial[512];
    __shared__ unsigned int stage_rec[CHUNK];
    __shared__ unsigned short stage_b[CHUNK];

    const int t = threadIdx.x;
    const int base = blockIdx.x * CHUNK;
    int n = E - base; if (n > CHUNK) n = CHUNK;

    hist[t] = 0; hist[t + 512] = 0;
    __syncthreads();

    unsigned int rec[8]; int bk[8]; int lr[8];
    #pragma unroll
    for (int k = 0; k < 8; ++k) {
        int i = t + k * 512;
        if (i < n) {
            int j = base + i;
            int d = dst_idx[j];
            int s = src_idx[j];
            int f = e_feat[j];
            bk[k]  = d >> LOGB;
            rec[k] = (unsigned)s | ((unsigned)(d & (NPB - 1)) << 17)
                                 | ((unsigned)f << 24);
            lr[k]  = atomicAdd(&hist[bk[k]], 1);
        } else bk[k] = -1;
    }
    __syncthreads();

    int a  = hist[2 * t];
    int b2 = hist[2 * t + 1];
    partial[t] = a + b2;
    __syncthreads();
    for (int off = 1; off < 512; off <<= 1) {
        int v = (t >= off) ? partial[t - off] : 0;
        __syncthreads();
        partial[t] += v;
        __syncthreads();
    }
    int pbase = partial[t] - (a + b2);
    start[2 * t]     = pbase;
    start[2 * t + 1] = pbase + a;
    __syncthreads();

    #pragma unroll
    for (int k = 0; k < 8; ++k) {
        if (bk[k] >= 0) {
            int pos = start[bk[k]] + lr[k];
            stage_rec[pos] = rec[k];
            stage_b[pos]   = (unsigned short)bk[k];
        }
    }
    for (int b = t; b < nbuk; b += 512) {
        int c = hist[b];
        if (c > 0) {
            int g0 = atomicAdd(&cursor[b], c);
            adjs[b] = g0 - start[b];
        }
    }
    __syncthreads();

    for (int i = t; i < n; i += 512) {
        int b  = stage_b[i];
        int dp = adjs[b] + i;
        unsigned int r = stage_rec[i];
        if (dp < CAP) {
            recs[(size_t)b * CAP + dp] = r;
        } else {
            int oi = atomicAdd(ovf_cnt, 1);
            if (oi < OVF_CAP) {
                int s  = r & 0x1FFFF;
                int dl = (r >> 17) & (NPB - 1);
                int f  = (r >> 24) & 7;
                ovf[oi] = make_int4((b << LOGB) | dl, s, f, 0);
            }
        }
    }
}

// ---------------- pass B: per-bucket node-sort + meta (u32 records out) ----------------
__global__ __launch_bounds__(256) void k_regroup(
    const int* __restrict__ cursor, const unsigned int* __restrict__ recs,
    unsigned int* __restrict__ recs2, int2* __restrict__ meta, int N)
{
    __shared__ int hist2[NPB];
    __shared__ int sc[NPB];
    __shared__ int nstart[NPB];
    __shared__ unsigned int rbuf[CAP];       // 8 KB

    const int t = threadIdx.x;
    const int b = blockIdx.x;
    int cnt = cursor[b]; if (cnt > CAP) cnt = CAP;

    for (int i = t; i < NPB; i += 256) hist2[i] = 0;
    __syncthreads();

    unsigned int r[8]; int nl[8]; int lr[8];
    #pragma unroll
    for (int k = 0; k < 8; ++k) {
        int i = t + k * 256;
        if (i < cnt) {
            r[k]  = recs[(size_t)b * CAP + i];
            nl[k] = (r[k] >> 17) & (NPB - 1);
            lr[k] = atomicAdd(&hist2[nl[k]], 1);
        } else nl[k] = -1;
    }
    __syncthreads();

    if (t < NPB) sc[t] = hist2[t];
    __syncthreads();
    for (int off = 1; off < NPB; off <<= 1) {
        int v = (t < NPB && t >= off) ? sc[t - off] : 0;
        __syncthreads();
        if (t < NPB) sc[t] += v;
        __syncthreads();
    }
    if (t < NPB) nstart[t] = sc[t] - hist2[t];
    __syncthreads();

    #pragma unroll
    for (int k = 0; k < 8; ++k) {
        if (nl[k] >= 0) {
            // compress: src(17) | ef(3)<<17
            rbuf[nstart[nl[k]] + lr[k]] = (r[k] & 0x1FFFF) | (((r[k] >> 24) & 7) << 17);
        }
    }
    __syncthreads();

    for (int i = t; i < cnt; i += 256)
        recs2[(size_t)b * CAP + i] = rbuf[i];

    const int node0 = b << LOGB;
    if (t < NPB) {
        int node = node0 + t;
        if (node < N)
            meta[node] = make_int2(b * CAP + nstart[t], hist2[t]);
    }
}

// ---------------- pass C: wave-per-node gather, bf16 emb ----------------
__global__ __launch_bounds__(256) void k_gather_bf16(
    const unsigned short* __restrict__ emb16, const float* __restrict__ weight,
    const float* __restrict__ sw,
    const int2* __restrict__ meta, const unsigned int* __restrict__ recs2,
    float* __restrict__ out, int N)
{
    __shared__ float ctab[8];
    int wave = threadIdx.x >> 6;
    int lane = threadIdx.x & 63;
    if (threadIdx.x < 8) {
        int f = threadIdx.x;
        float c = sw[0];
        c += (f == 0) ? sw[1] : 0.0f;
        c += (f == 2) ? sw[2] : 0.0f;
        c += (f == 4) ? sw[3] : 0.0f;
        c += (f == 6) ? sw[4] : 0.0f;
        ctab[f] = c;
    }
    __syncthreads();

    int node = blockIdx.x * 4 + wave;
    if (node >= N) return;

    int2 m = meta[node];
    int s = m.x, cnt = m.y;

    float a0=0.f,a1=0.f,a2=0.f,a3=0.f,a4=0.f,a5=0.f,a6=0.f,a7=0.f;

    for (int base = 0; base < cnt; base += 64) {
        int nch = cnt - base; if (nch > 64) nch = 64;
        unsigned int r = 0;
        if (lane < nch) r = recs2[s + base + lane];
        int j = 0;
        for (; j + 7 < nch; j += 8) {
            unsigned int r0 = __shfl(r, j    ), r1 = __shfl(r, j + 1);
            unsigned int r2 = __shfl(r, j + 2), r3 = __shfl(r, j + 3);
            unsigned int r4 = __shfl(r, j + 4), r5 = __shfl(r, j + 5);
            unsigned int r6 = __shfl(r, j + 6), r7 = __shfl(r, j + 7);
            float v0 = __uint_as_float((unsigned int)emb16[(size_t)(r0 & 0x1FFFF) * DIM + lane] << 16);
            float v1 = __uint_as_float((unsigned int)emb16[(size_t)(r1 & 0x1FFFF) * DIM + lane] << 16);
            float v2 = __uint_as_float((unsigned int)emb16[(size_t)(r2 & 0x1FFFF) * DIM + lane] << 16);
            float v3 = __uint_as_float((unsigned int)emb16[(size_t)(r3 & 0x1FFFF) * DIM + lane] << 16);
            float v4 = __uint_as_float((unsigned int)emb16[(size_t)(r4 & 0x1FFFF) * DIM + lane] << 16);
            float v5 = __uint_as_float((unsigned int)emb16[(size_t)(r5 & 0x1FFFF) * DIM + lane] << 16);
            float v6 = __uint_as_float((unsigned int)emb16[(size_t)(r6 & 0x1FFFF) * DIM + lane] << 16);
            float v7 = __uint_as_float((unsigned int)emb16[(size_t)(r7 & 0x1FFFF) * DIM + lane] << 16);
            a0 = fmaf(ctab[r0 >> 17], v0, a0);
            a1 = fmaf(ctab[r1 >> 17], v1, a1);
            a2 = fmaf(ctab[r2 >> 17], v2, a2);
            a3 = fmaf(ctab[r3 >> 17], v3, a3);
            a4 = fmaf(ctab[r4 >> 17], v4, a4);
            a5 = fmaf(ctab[r5 >> 17], v5, a5);
            a6 = fmaf(ctab[r6 >> 17], v6, a6);
            a7 = fmaf(ctab[r7 >> 17], v7, a7);
        }
        for (; j < nch; ++j) {
            unsigned int rj = __shfl(r, j);
            float v = __uint_as_float((unsigned int)emb16[(size_t)(rj & 0x1FFFF) * DIM + lane] << 16);
            a0 = fmaf(ctab[rj >> 17], v, a0);
        }
    }
    float acc = ((a0 + a1) + (a2 + a3)) + ((a4 + a5) + (a6 + a7));
    out[(size_t)node * DIM + lane] = acc * weight[lane];
}

// ---------------- pass C': fp32 gather (ws too small for emb16) ----------------
__global__ __launch_bounds__(256) void k_gather_f32(
    const float* __restrict__ emb, const float* __restrict__ weight,
    const float* __restrict__ sw,
    const int2* __restrict__ meta, const unsigned int* __restrict__ recs2,
    float* __restrict__ out, int N)
{
    __shared__ float ctab[8];
    int wave = threadIdx.x >> 6;
    int lane = threadIdx.x & 63;
    if (threadIdx.x < 8) {
        int f = threadIdx.x;
        float c = sw[0];
        c += (f == 0) ? sw[1] : 0.0f;
        c += (f == 2) ? sw[2] : 0.0f;
        c += (f == 4) ? sw[3] : 0.0f;
        c += (f == 6) ? sw[4] : 0.0f;
        ctab[f] = c;
    }
    __syncthreads();

    int node = blockIdx.x * 4 + wave;
    if (node >= N) return;

    int2 m = meta[node];
    int s = m.x, cnt = m.y;

    float a0=0.f,a1=0.f,a2=0.f,a3=0.f,a4=0.f,a5=0.f,a6=0.f,a7=0.f;

    for (int base = 0; base < cnt; base += 64) {
        int nch = cnt - base; if (nch > 64) nch = 64;
        unsigned int r = 0;
        if (lane < nch) r = recs2[s + base + lane];
        int j = 0;
        for (; j + 7 < nch; j += 8) {
            unsigned int r0 = __shfl(r, j    ), r1 = __shfl(r, j + 1);
            unsigned int r2 = __shfl(r, j + 2), r3 = __shfl(r, j + 3);
            unsigned int r4 = __shfl(r, j + 4), r5 = __shfl(r, j + 5);
            unsigned int r6 = __shfl(r, j + 6), r7 = __shfl(r, j + 7);
            a0 = fmaf(ctab[r0 >> 17], emb[(size_t)(r0 & 0x1FFFF) * DIM + lane], a0);
            a1 = fmaf(ctab[r1 >> 17], emb[(size_t)(r1 & 0x1FFFF) * DIM + lane], a1);
            a2 = fmaf(ctab[r2 >> 17], emb[(size_t)(r2 & 0x1FFFF) * DIM + lane], a2);
            a3 = fmaf(ctab[r3 >> 17], emb[(size_t)(r3 & 0x1FFFF) * DIM + lane], a3);
            a4 = fmaf(ctab[r4 >> 17], emb[(size_t)(r4 & 0x1FFFF) * DIM + lane], a4);
            a5 = fmaf(ctab[r5 >> 17], emb[(size_t)(r5 & 0x1FFFF) * DIM + lane], a5);
            a6 = fmaf(ctab[r6 >> 17], emb[(size_t)(r6 & 0x1FFFF) * DIM + lane], a6);
            a7 = fmaf(ctab[r7 >> 17], emb[(size_t)(r7 & 0x1FFFF) * DIM + lane], a7);
        }
        for (; j < nch; ++j) {
            unsigned int rj = __shfl(r, j);
            a0 = fmaf(ctab[rj >> 17], emb[(size_t)(rj & 0x1FFFF) * DIM + lane], a0);
        }
    }
    float acc = ((a0 + a1) + (a2 + a3)) + ((a4 + a5) + (a6 + a7));
    out[(size_t)node * DIM + lane] = acc * weight[lane];
}

// ---------------- pass D: overflow fixup (normally zero work) ----------------
__global__ __launch_bounds__(64) void k_overflow(
    const int* __restrict__ ovf_cnt, const int4* __restrict__ ovf,
    const float* __restrict__ emb, const float* __restrict__ weight,
    const float* __restrict__ sw, float* __restrict__ out)
{
    int m = *ovf_cnt; if (m > OVF_CAP) m = OVF_CAP;
    int lane = threadIdx.x;
    float s0 = sw[0], s1 = sw[1], s2 = sw[2], s3 = sw[3], s4 = sw[4];
    for (int i = blockIdx.x; i < m; i += gridDim.x) {
        int4 rec = ovf[i];
        int f = rec.z;
        float c = s0;
        c += (f == 0) ? s1 : 0.0f;
        c += (f == 2) ? s2 : 0.0f;
        c += (f == 4) ? s3 : 0.0f;
        c += (f == 6) ? s4 : 0.0f;
        float v = emb[(size_t)rec.y * DIM + lane] * weight[lane] * c;
        atomicAdd(&out[(size_t)rec.x * DIM + lane], v);
    }
}

// ---------------- fallback (tiny ws): round-1 atomic kernel ----------------
__global__ __launch_bounds__(256) void edge_scatter_kernel(
    const float* __restrict__ emb, const int* __restrict__ e_feat,
    const int* __restrict__ src_idx, const int* __restrict__ dst_idx,
    const float* __restrict__ weight, const float* __restrict__ sw,
    float* __restrict__ out, int n_edges) {
    int tid = blockIdx.x * blockDim.x + threadIdx.x;
    int edge = tid >> 4;
    int quad = tid & 15;
    if (edge >= n_edges) return;
    int ef = e_feat[edge];
    float coef = sw[0];
    coef += (ef == 0) ? sw[1] : 0.0f;
    coef += (ef == 2) ? sw[2] : 0.0f;
    coef += (ef == 4) ? sw[3] : 0.0f;
    coef += (ef == 6) ? sw[4] : 0.0f;
    int src = src_idx[edge], dst = dst_idx[edge];
    const float4 ev = *reinterpret_cast<const float4*>(emb + (size_t)src * DIM + quad * 4);
    const float4 wv = *reinterpret_cast<const float4*>(weight + quad * 4);
    float* op = out + (size_t)dst * DIM + quad * 4;
    atomicAdd(op + 0, ev.x * wv.x * coef);
    atomicAdd(op + 1, ev.y * wv.y * coef);
    atomicAdd(op + 2, ev.z * wv.z * coef);
    atomicAdd(op + 3, ev.w * wv.w * coef);
}

extern "C" void kernel_launch(void* const* d_in, const int* in_sizes, int n_in,
                              void* d_out, int out_size, void* d_ws, size_t ws_size,
                              hipStream_t stream) {
    const float* emb     = (const float*)d_in[0];
    const int*   e_feat  = (const int*)d_in[1];
    const int*   src_idx = (const int*)d_in[2];
    const int*   dst_idx = (const int*)d_in[3];
    const float* weight  = (const float*)d_in[4];
    const float* sw      = (const float*)d_in[5];
    float* out = (float*)d_out;

    const int E = in_sizes[1];
    const int N = in_sizes[0] / DIM;
    const int nbuk = (N + NPB - 1) / NPB;    // 782 for N=100000

    // ws: cursor[nbuk] | ovf_cnt | ovf[OVF_CAP] | recs[nbuk*CAP] u32
    //     | recs2[nbuk*CAP] u32 | meta[N] int2 | emb16[N*DIM] u16 (optional)
    size_t off_cursor = 0;
    size_t off_ovfcnt = off_cursor + (size_t)nbuk * 4;
    size_t off_ovf    = (off_ovfcnt + 4 + 15) & ~(size_t)15;
    size_t off_recs   = (off_ovf + (size_t)OVF_CAP * 16 + 15) & ~(size_t)15;
    size_t off_recs2  = (off_recs + (size_t)nbuk * CAP * 4 + 15) & ~(size_t)15;
    size_t off_meta   = (off_recs2 + (size_t)nbuk * CAP * 4 + 15) & ~(size_t)15;
    size_t off_emb16  = (off_meta + (size_t)N * 8 + 15) & ~(size_t)15;
    size_t needed     = off_emb16;                          // base (fp32 gather)
    size_t needed16   = off_emb16 + (size_t)N * DIM * 2;    // + bf16 table

    if (nbuk > NBUK_MAX || ws_size < needed) {
        hipMemsetAsync(d_out, 0, (size_t)out_size * sizeof(float), stream);
        int total = E * 16, block = 256;
        edge_scatter_kernel<<<(total + block - 1) / block, block, 0, stream>>>(
            emb, e_feat, src_idx, dst_idx, weight, sw, out, E);
        return;
    }
    const bool use_bf16 = (ws_size >= needed16);

    char* ws = (char*)d_ws;
    int*            cursor  = (int*)(ws + off_cursor);
    int*            ovf_cnt = (int*)(ws + off_ovfcnt);
    int4*           ovf     = (int4*)(ws + off_ovf);
    unsigned int*   recs    = (unsigned int*)(ws + off_recs);
    unsigned int*   recs2   = (unsigned int*)(ws + off_recs2);
    int2*           meta    = (int2*)(ws + off_meta);
    unsigned short* emb16   = (unsigned short*)(ws + off_emb16);

    hipMemsetAsync(cursor, 0, off_ovfcnt + 16 - off_cursor, stream);

    if (use_bf16) {
        int total4 = N * DIM / 4;
        k_convert<<<(total4 + 255) / 256, 256, 0, stream>>>(emb, emb16, total4);
    }

    k_bin<<<(E + CHUNK - 1) / CHUNK, 512, 0, stream>>>(
        e_feat, src_idx, dst_idx, cursor, ovf_cnt, ovf, recs, E, nbuk);

    k_regroup<<<nbuk, 256, 0, stream>>>(cursor, recs, recs2, meta, N);

    if (use_bf16) {
        k_gather_bf16<<<(N + 3) / 4, 256, 0, stream>>>(
            emb16, weight, sw, meta, recs2, out, N);
    } else {
        k_gather_f32<<<(N + 3) / 4, 256, 0, stream>>>(
            emb, weight, sw, meta, recs2, out, N);
    }

    k_overflow<<<64, 64, 0, stream>>>(ovf_cnt, ovf, emb, weight, sw, out);
}

// Round 17
// 163.493 us; speedup vs baseline: 1.0403x; 1.0161x over previous
//
#include <hip/hip_runtime.h>

// out = segment_sum( coef(e_feat) * (emb[src] ⊙ weight), dst, N )
// coef(v) = sw[0] + (v==0)*sw[1] + (v==2)*sw[2] + (v==4)*sw[3] + (v==6)*sw[4]
//
// R17 = R16 pipeline with preprocessing latency cuts:
//   - convert folded into k_bin prologue (one fewer dispatch; streams under
//     bin's barrier latency).
//   - k_bin 1024-entry scan: Hillis-Steele (18 barriers) -> wave shfl scan (2).
//   - k_regroup 128-entry scan: same treatment (14 -> 2 barriers).
//   - gather: bf16 emb + u32 records (measured 54us, absmax 0.031 ok).

#define DIM 64
#define LOGB 7
#define NPB 128
#define NBUK_MAX 1024
#define CAP 2048
#define CHUNK 4096
#define OVF_CAP 8192

// ---------------- pass A: convert prologue + LDS-staged binning ----------------
__global__ __launch_bounds__(512) void k_bin(
    const int* __restrict__ e_feat, const int* __restrict__ src_idx,
    const int* __restrict__ dst_idx, const float* __restrict__ emb,
    unsigned short* __restrict__ emb16, int do_convert, int total4,
    int* __restrict__ cursor, int* __restrict__ ovf_cnt, int4* __restrict__ ovf,
    unsigned int* __restrict__ recs, int E, int nbuk)
{
    __shared__ int hist[NBUK_MAX];
    __shared__ int start[NBUK_MAX];
    __shared__ int adjs[NBUK_MAX];
    __shared__ int wtot[8];
    __shared__ unsigned int stage_rec[CHUNK];
    __shared__ unsigned short stage_b[CHUNK];

    const int t = threadIdx.x;
    const int lane = t & 63;
    const int wv   = t >> 6;

    // ---- prologue: fp32 -> bf16 convert (grid-stride, hides under barriers) ----
    if (do_convert) {
        for (int i = blockIdx.x * 512 + t; i < total4; i += gridDim.x * 512) {
            float4 v = reinterpret_cast<const float4*>(emb)[i];
            ushort4 o;
            unsigned int x;
            x = __float_as_uint(v.x); o.x = (unsigned short)((x + 0x7FFF + ((x >> 16) & 1)) >> 16);
            x = __float_as_uint(v.y); o.y = (unsigned short)((x + 0x7FFF + ((x >> 16) & 1)) >> 16);
            x = __float_as_uint(v.z); o.z = (unsigned short)((x + 0x7FFF + ((x >> 16) & 1)) >> 16);
            x = __float_as_uint(v.w); o.w = (unsigned short)((x + 0x7FFF + ((x >> 16) & 1)) >> 16);
            reinterpret_cast<ushort4*>(emb16)[i] = o;
        }
    }

    const int base = blockIdx.x * CHUNK;
    int n = E - base; if (n > CHUNK) n = CHUNK;

    hist[t] = 0; hist[t + 512] = 0;
    __syncthreads();

    unsigned int rec[8]; int bk[8]; int lr[8];
    #pragma unroll
    for (int k = 0; k < 8; ++k) {
        int i = t + k * 512;
        if (i < n) {
            int j = base + i;
            int d = dst_idx[j];
            int s = src_idx[j];
            int f = e_feat[j];
            bk[k]  = d >> LOGB;
            rec[k] = (unsigned)s | ((unsigned)(d & (NPB - 1)) << 17)
                                 | ((unsigned)f << 24);
            lr[k]  = atomicAdd(&hist[bk[k]], 1);
        } else bk[k] = -1;
    }
    __syncthreads();

    // ---- exclusive scan of hist[0..1024): wave shfl scan (2 barriers) ----
    int a  = hist[2 * t];
    int b2 = hist[2 * t + 1];
    int p  = a + b2;
    int sc = p;
    #pragma unroll
    for (int off = 1; off < 64; off <<= 1) {
        int u = __shfl_up(sc, off);
        if (lane >= off) sc += u;
    }
    if (lane == 63) wtot[wv] = sc;
    __syncthreads();
    if (t == 0) {
        int acc = 0;
        #pragma unroll
        for (int w = 0; w < 8; ++w) { int v = wtot[w]; wtot[w] = acc; acc += v; }
    }
    __syncthreads();
    int excl = sc - p + wtot[wv];           // exclusive over pairs
    start[2 * t]     = excl;
    start[2 * t + 1] = excl + a;
    __syncthreads();

    #pragma unroll
    for (int k = 0; k < 8; ++k) {
        if (bk[k] >= 0) {
            int pos = start[bk[k]] + lr[k];
            stage_rec[pos] = rec[k];
            stage_b[pos]   = (unsigned short)bk[k];
        }
    }
    for (int b = t; b < nbuk; b += 512) {
        int c = hist[b];
        if (c > 0) {
            int g0 = atomicAdd(&cursor[b], c);
            adjs[b] = g0 - start[b];
        }
    }
    __syncthreads();

    for (int i = t; i < n; i += 512) {
        int b  = stage_b[i];
        int dp = adjs[b] + i;
        unsigned int r = stage_rec[i];
        if (dp < CAP) {
            recs[(size_t)b * CAP + dp] = r;
        } else {
            int oi = atomicAdd(ovf_cnt, 1);
            if (oi < OVF_CAP) {
                int s  = r & 0x1FFFF;
                int dl = (r >> 17) & (NPB - 1);
                int f  = (r >> 24) & 7;
                ovf[oi] = make_int4((b << LOGB) | dl, s, f, 0);
            }
        }
    }
}

// ---------------- pass B: per-bucket node-sort + meta (u32 records out) ----------------
__global__ __launch_bounds__(256) void k_regroup(
    const int* __restrict__ cursor, const unsigned int* __restrict__ recs,
    unsigned int* __restrict__ recs2, int2* __restrict__ meta, int N)
{
    __shared__ int hist2[NPB];
    __shared__ int nstart[NPB];
    __shared__ int wtot2[2];
    __shared__ unsigned int rbuf[CAP];       // 8 KB

    const int t = threadIdx.x;
    const int b = blockIdx.x;
    const int lane = t & 63;
    const int wv   = t >> 6;
    int cnt = cursor[b]; if (cnt > CAP) cnt = CAP;

    if (t < NPB) hist2[t] = 0;
    __syncthreads();

    unsigned int r[8]; int nl[8]; int lr[8];
    #pragma unroll
    for (int k = 0; k < 8; ++k) {
        int i = t + k * 256;
        if (i < cnt) {
            r[k]  = recs[(size_t)b * CAP + i];
            nl[k] = (r[k] >> 17) & (NPB - 1);
            lr[k] = atomicAdd(&hist2[nl[k]], 1);
        } else nl[k] = -1;
    }
    __syncthreads();

    // ---- exclusive scan of hist2[0..128): 2-wave shfl scan (2 barriers) ----
    int v  = (t < NPB) ? hist2[t] : 0;
    int sc = v;
    #pragma unroll
    for (int off = 1; off < 64; off <<= 1) {
        int u = __shfl_up(sc, off);
        if (lane >= off) sc += u;
    }
    if (t < NPB && lane == 63) wtot2[wv] = sc;
    __syncthreads();
    if (t < NPB) nstart[t] = sc - v + ((wv == 1) ? wtot2[0] : 0);
    __syncthreads();

    #pragma unroll
    for (int k = 0; k < 8; ++k) {
        if (nl[k] >= 0) {
            // compress: src(17) | ef(3)<<17
            rbuf[nstart[nl[k]] + lr[k]] = (r[k] & 0x1FFFF) | (((r[k] >> 24) & 7) << 17);
        }
    }
    __syncthreads();

    for (int i = t; i < cnt; i += 256)
        recs2[(size_t)b * CAP + i] = rbuf[i];

    const int node0 = b << LOGB;
    if (t < NPB) {
        int node = node0 + t;
        if (node < N)
            meta[node] = make_int2(b * CAP + nstart[t], hist2[t]);
    }
}

// ---------------- pass C: wave-per-node gather, bf16 emb ----------------
__global__ __launch_bounds__(256) void k_gather_bf16(
    const unsigned short* __restrict__ emb16, const float* __restrict__ weight,
    const float* __restrict__ sw,
    const int2* __restrict__ meta, const unsigned int* __restrict__ recs2,
    float* __restrict__ out, int N)
{
    __shared__ float ctab[8];
    int wave = threadIdx.x >> 6;
    int lane = threadIdx.x & 63;
    if (threadIdx.x < 8) {
        int f = threadIdx.x;
        float c = sw[0];
        c += (f == 0) ? sw[1] : 0.0f;
        c += (f == 2) ? sw[2] : 0.0f;
        c += (f == 4) ? sw[3] : 0.0f;
        c += (f == 6) ? sw[4] : 0.0f;
        ctab[f] = c;
    }
    __syncthreads();

    int node = blockIdx.x * 4 + wave;
    if (node >= N) return;

    int2 m = meta[node];
    int s = m.x, cnt = m.y;

    float a0=0.f,a1=0.f,a2=0.f,a3=0.f,a4=0.f,a5=0.f,a6=0.f,a7=0.f;

    for (int base = 0; base < cnt; base += 64) {
        int nch = cnt - base; if (nch > 64) nch = 64;
        unsigned int r = 0;
        if (lane < nch) r = recs2[s + base + lane];
        int j = 0;
        for (; j + 7 < nch; j += 8) {
            unsigned int r0 = __shfl(r, j    ), r1 = __shfl(r, j + 1);
            unsigned int r2 = __shfl(r, j + 2), r3 = __shfl(r, j + 3);
            unsigned int r4 = __shfl(r, j + 4), r5 = __shfl(r, j + 5);
            unsigned int r6 = __shfl(r, j + 6), r7 = __shfl(r, j + 7);
            float v0 = __uint_as_float((unsigned int)emb16[(size_t)(r0 & 0x1FFFF) * DIM + lane] << 16);
            float v1 = __uint_as_float((unsigned int)emb16[(size_t)(r1 & 0x1FFFF) * DIM + lane] << 16);
            float v2 = __uint_as_float((unsigned int)emb16[(size_t)(r2 & 0x1FFFF) * DIM + lane] << 16);
            float v3 = __uint_as_float((unsigned int)emb16[(size_t)(r3 & 0x1FFFF) * DIM + lane] << 16);
            float v4 = __uint_as_float((unsigned int)emb16[(size_t)(r4 & 0x1FFFF) * DIM + lane] << 16);
            float v5 = __uint_as_float((unsigned int)emb16[(size_t)(r5 & 0x1FFFF) * DIM + lane] << 16);
            float v6 = __uint_as_float((unsigned int)emb16[(size_t)(r6 & 0x1FFFF) * DIM + lane] << 16);
            float v7 = __uint_as_float((unsigned int)emb16[(size_t)(r7 & 0x1FFFF) * DIM + lane] << 16);
            a0 = fmaf(ctab[r0 >> 17], v0, a0);
            a1 = fmaf(ctab[r1 >> 17], v1, a1);
            a2 = fmaf(ctab[r2 >> 17], v2, a2);
            a3 = fmaf(ctab[r3 >> 17], v3, a3);
            a4 = fmaf(ctab[r4 >> 17], v4, a4);
            a5 = fmaf(ctab[r5 >> 17], v5, a5);
            a6 = fmaf(ctab[r6 >> 17], v6, a6);
            a7 = fmaf(ctab[r7 >> 17], v7, a7);
        }
        for (; j < nch; ++j) {
            unsigned int rj = __shfl(r, j);
            float v = __uint_as_float((unsigned int)emb16[(size_t)(rj & 0x1FFFF) * DIM + lane] << 16);
            a0 = fmaf(ctab[rj >> 17], v, a0);
        }
    }
    float acc = ((a0 + a1) + (a2 + a3)) + ((a4 + a5) + (a6 + a7));
    out[(size_t)node * DIM + lane] = acc * weight[lane];
}

// ---------------- pass C': fp32 gather (ws too small for emb16) ----------------
__global__ __launch_bounds__(256) void k_gather_f32(
    const float* __restrict__ emb, const float* __restrict__ weight,
    const float* __restrict__ sw,
    const int2* __restrict__ meta, const unsigned int* __restrict__ recs2,
    float* __restrict__ out, int N)
{
    __shared__ float ctab[8];
    int wave = threadIdx.x >> 6;
    int lane = threadIdx.x & 63;
    if (threadIdx.x < 8) {
        int f = threadIdx.x;
        float c = sw[0];
        c += (f == 0) ? sw[1] : 0.0f;
        c += (f == 2) ? sw[2] : 0.0f;
        c += (f == 4) ? sw[3] : 0.0f;
        c += (f == 6) ? sw[4] : 0.0f;
        ctab[f] = c;
    }
    __syncthreads();

    int node = blockIdx.x * 4 + wave;
    if (node >= N) return;

    int2 m = meta[node];
    int s = m.x, cnt = m.y;

    float a0=0.f,a1=0.f,a2=0.f,a3=0.f,a4=0.f,a5=0.f,a6=0.f,a7=0.f;

    for (int base = 0; base < cnt; base += 64) {
        int nch = cnt - base; if (nch > 64) nch = 64;
        unsigned int r = 0;
        if (lane < nch) r = recs2[s + base + lane];
        int j = 0;
        for (; j + 7 < nch; j += 8) {
            unsigned int r0 = __shfl(r, j    ), r1 = __shfl(r, j + 1);
            unsigned int r2 = __shfl(r, j + 2), r3 = __shfl(r, j + 3);
            unsigned int r4 = __shfl(r, j + 4), r5 = __shfl(r, j + 5);
            unsigned int r6 = __shfl(r, j + 6), r7 = __shfl(r, j + 7);
            a0 = fmaf(ctab[r0 >> 17], emb[(size_t)(r0 & 0x1FFFF) * DIM + lane], a0);
            a1 = fmaf(ctab[r1 >> 17], emb[(size_t)(r1 & 0x1FFFF) * DIM + lane], a1);
            a2 = fmaf(ctab[r2 >> 17], emb[(size_t)(r2 & 0x1FFFF) * DIM + lane], a2);
            a3 = fmaf(ctab[r3 >> 17], emb[(size_t)(r3 & 0x1FFFF) * DIM + lane], a3);
            a4 = fmaf(ctab[r4 >> 17], emb[(size_t)(r4 & 0x1FFFF) * DIM + lane], a4);
            a5 = fmaf(ctab[r5 >> 17], emb[(size_t)(r5 & 0x1FFFF) * DIM + lane], a5);
            a6 = fmaf(ctab[r6 >> 17], emb[(size_t)(r6 & 0x1FFFF) * DIM + lane], a6);
            a7 = fmaf(ctab[r7 >> 17], emb[(size_t)(r7 & 0x1FFFF) * DIM + lane], a7);
        }
        for (; j < nch; ++j) {
            unsigned int rj = __shfl(r, j);
            a0 = fmaf(ctab[rj >> 17], emb[(size_t)(rj & 0x1FFFF) * DIM + lane], a0);
        }
    }
    float acc = ((a0 + a1) + (a2 + a3)) + ((a4 + a5) + (a6 + a7));
    out[(size_t)node * DIM + lane] = acc * weight[lane];
}

// ---------------- pass D: overflow fixup (normally zero work) ----------------
__global__ __launch_bounds__(64) void k_overflow(
    const int* __restrict__ ovf_cnt, const int4* __restrict__ ovf,
    const float* __restrict__ emb, const float* __restrict__ weight,
    const float* __restrict__ sw, float* __restrict__ out)
{
    int m = *ovf_cnt; if (m > OVF_CAP) m = OVF_CAP;
    int lane = threadIdx.x;
    float s0 = sw[0], s1 = sw[1], s2 = sw[2], s3 = sw[3], s4 = sw[4];
    for (int i = blockIdx.x; i < m; i += gridDim.x) {
        int4 rec = ovf[i];
        int f = rec.z;
        float c = s0;
        c += (f == 0) ? s1 : 0.0f;
        c += (f == 2) ? s2 : 0.0f;
        c += (f == 4) ? s3 : 0.0f;
        c += (f == 6) ? s4 : 0.0f;
        float v = emb[(size_t)rec.y * DIM + lane] * weight[lane] * c;
        atomicAdd(&out[(size_t)rec.x * DIM + lane], v);
    }
}

// ---------------- fallback (tiny ws): round-1 atomic kernel ----------------
__global__ __launch_bounds__(256) void edge_scatter_kernel(
    const float* __restrict__ emb, const int* __restrict__ e_feat,
    const int* __restrict__ src_idx, const int* __restrict__ dst_idx,
    const float* __restrict__ weight, const float* __restrict__ sw,
    float* __restrict__ out, int n_edges) {
    int tid = blockIdx.x * blockDim.x + threadIdx.x;
    int edge = tid >> 4;
    int quad = tid & 15;
    if (edge >= n_edges) return;
    int ef = e_feat[edge];
    float coef = sw[0];
    coef += (ef == 0) ? sw[1] : 0.0f;
    coef += (ef == 2) ? sw[2] : 0.0f;
    coef += (ef == 4) ? sw[3] : 0.0f;
    coef += (ef == 6) ? sw[4] : 0.0f;
    int src = src_idx[edge], dst = dst_idx[edge];
    const float4 ev = *reinterpret_cast<const float4*>(emb + (size_t)src * DIM + quad * 4);
    const float4 wv = *reinterpret_cast<const float4*>(weight + quad * 4);
    float* op = out + (size_t)dst * DIM + quad * 4;
    atomicAdd(op + 0, ev.x * wv.x * coef);
    atomicAdd(op + 1, ev.y * wv.y * coef);
    atomicAdd(op + 2, ev.z * wv.z * coef);
    atomicAdd(op + 3, ev.w * wv.w * coef);
}

extern "C" void kernel_launch(void* const* d_in, const int* in_sizes, int n_in,
                              void* d_out, int out_size, void* d_ws, size_t ws_size,
                              hipStream_t stream) {
    const float* emb     = (const float*)d_in[0];
    const int*   e_feat  = (const int*)d_in[1];
    const int*   src_idx = (const int*)d_in[2];
    const int*   dst_idx = (const int*)d_in[3];
    const float* weight  = (const float*)d_in[4];
    const float* sw      = (const float*)d_in[5];
    float* out = (float*)d_out;

    const int E = in_sizes[1];
    const int N = in_sizes[0] / DIM;
    const int nbuk = (N + NPB - 1) / NPB;    // 782 for N=100000

    // ws: cursor[nbuk] | ovf_cnt | ovf[OVF_CAP] | recs[nbuk*CAP] u32
    //     | recs2[nbuk*CAP] u32 | meta[N] int2 | emb16[N*DIM] u16 (optional)
    size_t off_cursor = 0;
    size_t off_ovfcnt = off_cursor + (size_t)nbuk * 4;
    size_t off_ovf    = (off_ovfcnt + 4 + 15) & ~(size_t)15;
    size_t off_recs   = (off_ovf + (size_t)OVF_CAP * 16 + 15) & ~(size_t)15;
    size_t off_recs2  = (off_recs + (size_t)nbuk * CAP * 4 + 15) & ~(size_t)15;
    size_t off_meta   = (off_recs2 + (size_t)nbuk * CAP * 4 + 15) & ~(size_t)15;
    size_t off_emb16  = (off_meta + (size_t)N * 8 + 15) & ~(size_t)15;
    size_t needed     = off_emb16;                          // base (fp32 gather)
    size_t needed16   = off_emb16 + (size_t)N * DIM * 2;    // + bf16 table

    if (nbuk > NBUK_MAX || ws_size < needed) {
        hipMemsetAsync(d_out, 0, (size_t)out_size * sizeof(float), stream);
        int total = E * 16, block = 256;
        edge_scatter_kernel<<<(total + block - 1) / block, block, 0, stream>>>(
            emb, e_feat, src_idx, dst_idx, weight, sw, out, E);
        return;
    }
    const bool use_bf16 = (ws_size >= needed16) && (N * DIM % 4 == 0);

    char* ws = (char*)d_ws;
    int*            cursor  = (int*)(ws + off_cursor);
    int*            ovf_cnt = (int*)(ws + off_ovfcnt);
    int4*           ovf     = (int4*)(ws + off_ovf);
    unsigned int*   recs    = (unsigned int*)(ws + off_recs);
    unsigned int*   recs2   = (unsigned int*)(ws + off_recs2);
    int2*           meta    = (int2*)(ws + off_meta);
    unsigned short* emb16   = (unsigned short*)(ws + off_emb16);

    hipMemsetAsync(cursor, 0, off_ovfcnt + 16 - off_cursor, stream);

    k_bin<<<(E + CHUNK - 1) / CHUNK, 512, 0, stream>>>(
        e_feat, src_idx, dst_idx, emb, emb16, use_bf16 ? 1 : 0, N * DIM / 4,
        cursor, ovf_cnt, ovf, recs, E, nbuk);

    k_regroup<<<nbuk, 256, 0, stream>>>(cursor, recs, recs2, meta, N);

    if (use_bf16) {
        k_gather_bf16<<<(N + 3) / 4, 256, 0, stream>>>(
            emb16, weight, sw, meta, recs2, out, N);
    } else {
        k_gather_f32<<<(N + 3) / 4, 256, 0, stream>>>(
            emb, weight, sw, meta, recs2, out, N);
    }

    k_overflow<<<64, 64, 0, stream>>>(ovf_cnt, ovf, emb, weight, sw, out);
}